// Round 1
// baseline (203.288 us; speedup 1.0000x reference)
//
#include <hip/hip_runtime.h>
#include <math.h>

#define NB 2
#define NN 1024
#define NH 64
#define NK 8
#define NPTS (NB * NN)

// Prep kernel: blocks 0..7 compute per-point {start_x, start_y, cos(h), sin(h)};
// block 8 builds the packed per-h weight table:
//   wpk[h][0..4] = W1[f][h] - mean_h(W1[f][:])   (mean-centered -> LN mu folded in)
//   wpk[h][5]    = b1[h] - mean(b1)
//   wpk[h][6]    = gamma[h], wpk[h][7] = beta[h]
//   wpk[h][8..15]= W2[h][0..7]
__global__ void prep_kernel(const float* __restrict__ rv,
                            const float* __restrict__ W1,
                            const float* __restrict__ b1,
                            const float* __restrict__ gamma,
                            const float* __restrict__ beta,
                            const float* __restrict__ W2,
                            float* __restrict__ pt,
                            float* __restrict__ wpk) {
    const int tid = threadIdx.x;
    const int bid = blockIdx.x;
    if (bid < 8) {
        const int idx = bid * 256 + tid;  // 0..2047
        const float x0 = rv[idx * 4 + 0];
        const float y0 = rv[idx * 4 + 1];
        const float x1 = rv[idx * 4 + 2];
        const float y1 = rv[idx * 4 + 3];
        const float hd = atan2f(y1 - y0, x1 - x0);
        float4 o;
        o.x = x0; o.y = y0; o.z = cosf(hd); o.w = sinf(hd);
        reinterpret_cast<float4*>(pt)[idx] = o;
    } else {
        __shared__ float mean[6];
        if (tid < 5) {
            float m = 0.f;
            for (int h = 0; h < NH; ++h) m += W1[tid * NH + h];
            mean[tid] = m * (1.f / NH);
        } else if (tid == 5) {
            float m = 0.f;
            for (int h = 0; h < NH; ++h) m += b1[h];
            mean[5] = m * (1.f / NH);
        }
        __syncthreads();
        if (tid < NH) {
            const int h = tid;
            float p[16];
            for (int f = 0; f < 5; ++f) p[f] = W1[f * NH + h] - mean[f];
            p[5] = b1[h] - mean[5];
            p[6] = gamma[h];
            p[7] = beta[h];
            for (int k = 0; k < NK; ++k) p[8 + k] = W2[h * NK + k];
            for (int c = 0; c < 16; ++c) wpk[h * 16 + c] = p[c];
        }
    }
}

// Main kernel: one thread per (b,i,j) pair. j contiguous along threadIdx.x
// (coalesced per-j loads + coalesced stores); per-i point data is
// block-uniform (scalar loads); weight table reads are block-uniform
// (-> s_load, no LDS, no per-lane VMEM).
__global__ __launch_bounds__(256) void rpe_kernel(const float* __restrict__ pt,
                                                  const float* __restrict__ wpk,
                                                  const float* __restrict__ b2,
                                                  float* __restrict__ out) {
    const int j = blockIdx.x * 256 + threadIdx.x;
    const int i = blockIdx.y;
    const int b = blockIdx.z;

    const float4 pi4 = reinterpret_cast<const float4*>(pt)[b * NN + i];
    const float4 pj4 = reinterpret_cast<const float4*>(pt)[b * NN + j];
    const float dx = pi4.x - pj4.x;
    const float dy = pi4.y - pj4.y;
    const float ci = pi4.z, si = pi4.w;
    const float cj = pj4.z, sj = pj4.w;

    const float g0 = logf(sqrtf(fmaf(dx, dx, dy * dy)) + 1e-5f);  // feat_dist
    const float g1 = fmaf(ci, cj, si * sj);                        // cos(hi-hj)
    const float g2 = fmaf(si, cj, -ci * sj);                       // sin(hi-hj)
    const float g3 = fmaf(dx, ci, dy * si);                        // rel_x
    const float g4 = fmaf(dy, ci, -dx * si);                       // rel_y

    float hc[NH];
    float var = 0.f;
#pragma unroll
    for (int h = 0; h < NH; ++h) {
        const float* p = wpk + h * 16;
        float t = fmaf(g0, p[0], p[5]);
        t = fmaf(g1, p[1], t);
        t = fmaf(g2, p[2], t);
        t = fmaf(g3, p[3], t);
        t = fmaf(g4, p[4], t);
        hc[h] = t;
        var = fmaf(t, t, var);
    }
    const float inv = rsqrtf(fmaf(var, 1.f / NH, 1e-5f));

    float acc[NK];
#pragma unroll
    for (int k = 0; k < NK; ++k) acc[k] = b2[k];
#pragma unroll
    for (int h = 0; h < NH; ++h) {
        const float* p = wpk + h * 16;
        float y = fmaf(hc[h] * inv, p[6], p[7]);
        y = fmaxf(y, 0.f);
#pragma unroll
        for (int k = 0; k < NK; ++k) acc[k] = fmaf(y, p[8 + k], acc[k]);
    }

    const size_t plane = (size_t)NN * NN;
    const size_t base = (size_t)(b * NK) * plane + (size_t)i * NN + j;
#pragma unroll
    for (int k = 0; k < NK; ++k) out[base + (size_t)k * plane] = acc[k];
}

extern "C" void kernel_launch(void* const* d_in, const int* in_sizes, int n_in,
                              void* d_out, int out_size, void* d_ws, size_t ws_size,
                              hipStream_t stream) {
    const float* rv    = (const float*)d_in[0];
    const float* W1    = (const float*)d_in[1];
    const float* b1    = (const float*)d_in[2];
    const float* gamma = (const float*)d_in[3];
    const float* beta  = (const float*)d_in[4];
    const float* W2    = (const float*)d_in[5];
    const float* b2    = (const float*)d_in[6];
    float* out = (float*)d_out;

    float* ws  = (float*)d_ws;
    float* pt  = ws;               // 2048 * 4 floats = 32 KB
    float* wpk = ws + NPTS * 4;    // 64 * 16 floats  =  4 KB

    prep_kernel<<<9, 256, 0, stream>>>(rv, W1, b1, gamma, beta, W2, pt, wpk);

    dim3 grid(NN / 256, NN, NB);
    rpe_kernel<<<grid, 256, 0, stream>>>(pt, wpk, b2, out);
}

// Round 2
// 104.273 us; speedup vs baseline: 1.9496x; 1.9496x over previous
//
#include <hip/hip_runtime.h>
#include <math.h>

#define NB 2
#define NN 1024
#define NH 64
#define NK 8
#define NPTS (NB * NN)

typedef float f2 __attribute__((ext_vector_type(2)));

// Packed weight layout, per h-pair p in [0,32), 32 floats each (128 B):
//   base = p*32
//   [base + 2c + e], c=0..7 : coef c for h = 2p+e
//       c 0..4 = W1 column (mean-centered -> LN mu folded in)
//       c 5    = b1 (centered), c 6 = gamma, c 7 = beta
//   [base + 16 + 8e + k]    : W2[h=2p+e][k], k=0..7
__global__ void prep_kernel(const float* __restrict__ rv,
                            const float* __restrict__ W1,
                            const float* __restrict__ b1,
                            const float* __restrict__ gamma,
                            const float* __restrict__ beta,
                            const float* __restrict__ W2,
                            float* __restrict__ pt,
                            float* __restrict__ wpk) {
    const int tid = threadIdx.x;
    const int bid = blockIdx.x;
    if (bid < 8) {
        const int idx = bid * 256 + tid;  // 0..2047
        const float x0 = rv[idx * 4 + 0];
        const float y0 = rv[idx * 4 + 1];
        const float vx = rv[idx * 4 + 2] - x0;
        const float vy = rv[idx * 4 + 3] - y0;
        const float rinv = rsqrtf(fmaf(vx, vx, vy * vy));
        float4 o;
        o.x = x0; o.y = y0; o.z = vx * rinv; o.w = vy * rinv;
        reinterpret_cast<float4*>(pt)[idx] = o;
    } else {
        __shared__ float mean[6];
        if (tid < 5) {
            float m = 0.f;
            for (int h = 0; h < NH; ++h) m += W1[tid * NH + h];
            mean[tid] = m * (1.f / NH);
        } else if (tid == 5) {
            float m = 0.f;
            for (int h = 0; h < NH; ++h) m += b1[h];
            mean[5] = m * (1.f / NH);
        }
        __syncthreads();
        if (tid < NH) {
            const int h = tid;
            const int p = h >> 1, e = h & 1;
            const int base = p * 32;
            for (int f = 0; f < 5; ++f) wpk[base + 2 * f + e] = W1[f * NH + h] - mean[f];
            wpk[base + 10 + e] = b1[h] - mean[5];
            wpk[base + 12 + e] = gamma[h];
            wpk[base + 14 + e] = beta[h];
            for (int k = 0; k < NK; ++k) wpk[base + 16 + 8 * e + k] = W2[h * NK + k];
        }
    }
}

// One thread per (b,i,j). j along threadIdx.x (coalesced loads/stores).
// Weight reads are block-uniform (scalar loads); all heavy math is float2
// packed (v_pk_fma_f32). hc kept fully in registers (launch_bounds caps
// occupancy to allow ~128 VGPRs).
__global__ __launch_bounds__(256, 2) void rpe_kernel(const float* __restrict__ pt,
                                                     const float* __restrict__ wpk,
                                                     const float* __restrict__ b2,
                                                     float* __restrict__ out) {
    const int j = blockIdx.x * 256 + threadIdx.x;
    const int i = blockIdx.y;
    const int b = blockIdx.z;

    const float4 pi4 = reinterpret_cast<const float4*>(pt)[b * NN + i];
    const float4 pj4 = reinterpret_cast<const float4*>(pt)[b * NN + j];
    const float dx = pi4.x - pj4.x;
    const float dy = pi4.y - pj4.y;
    const float ci = pi4.z, si = pi4.w;
    const float cj = pj4.z, sj = pj4.w;

    const float g0 = logf(sqrtf(fmaf(dx, dx, dy * dy)) + 1e-5f);  // feat_dist
    const float g1 = fmaf(ci, cj, si * sj);                        // cos(hi-hj)
    const float g2 = fmaf(si, cj, -ci * sj);                       // sin(hi-hj)
    const float g3 = fmaf(dx, ci, dy * si);                        // rel_x
    const float g4 = fmaf(dy, ci, -dx * si);                       // rel_y

    const f2 G0 = {g0, g0}, G1 = {g1, g1}, G2 = {g2, g2}, G3 = {g3, g3}, G4 = {g4, g4};

    f2 hc[NH / 2];
    f2 var2 = {0.f, 0.f};
#pragma unroll
    for (int p = 0; p < NH / 2; ++p) {
        const float* q = wpk + p * 32;
        const f2 w0 = *(const f2*)(q + 0);
        const f2 w1 = *(const f2*)(q + 2);
        const f2 w2 = *(const f2*)(q + 4);
        const f2 w3 = *(const f2*)(q + 6);
        const f2 w4 = *(const f2*)(q + 8);
        const f2 bb = *(const f2*)(q + 10);
        f2 t = __builtin_elementwise_fma(G0, w0, bb);
        t = __builtin_elementwise_fma(G1, w1, t);
        t = __builtin_elementwise_fma(G2, w2, t);
        t = __builtin_elementwise_fma(G3, w3, t);
        t = __builtin_elementwise_fma(G4, w4, t);
        hc[p] = t;
        var2 = __builtin_elementwise_fma(t, t, var2);
    }
    const float inv = rsqrtf(fmaf(var2.x + var2.y, 1.f / NH, 1e-5f));
    const f2 INV = {inv, inv};
    const f2 Z2 = {0.f, 0.f};

    f2 acc[NK / 2];
#pragma unroll
    for (int kk = 0; kk < NK / 2; ++kk) acc[kk] = *(const f2*)(b2 + 2 * kk);

#pragma unroll
    for (int p = 0; p < NH / 2; ++p) {
        const float* q = wpk + p * 32;
        const f2 gam = *(const f2*)(q + 12);
        const f2 bet = *(const f2*)(q + 14);
        const f2 u = hc[p] * INV;
        f2 y = __builtin_elementwise_fma(u, gam, bet);
        y = __builtin_elementwise_max(y, Z2);
        const f2* w2a = (const f2*)(q + 16);
        const f2* w2b = (const f2*)(q + 24);
        const f2 ya = {y.x, y.x};
        const f2 yb = {y.y, y.y};
#pragma unroll
        for (int kk = 0; kk < NK / 2; ++kk) acc[kk] = __builtin_elementwise_fma(ya, w2a[kk], acc[kk]);
#pragma unroll
        for (int kk = 0; kk < NK / 2; ++kk) acc[kk] = __builtin_elementwise_fma(yb, w2b[kk], acc[kk]);
    }

    const size_t plane = (size_t)NN * NN;
    const size_t base = (size_t)(b * NK) * plane + (size_t)i * NN + j;
#pragma unroll
    for (int kk = 0; kk < NK / 2; ++kk) {
        out[base + (size_t)(2 * kk + 0) * plane] = acc[kk].x;
        out[base + (size_t)(2 * kk + 1) * plane] = acc[kk].y;
    }
}

extern "C" void kernel_launch(void* const* d_in, const int* in_sizes, int n_in,
                              void* d_out, int out_size, void* d_ws, size_t ws_size,
                              hipStream_t stream) {
    const float* rv    = (const float*)d_in[0];
    const float* W1    = (const float*)d_in[1];
    const float* b1    = (const float*)d_in[2];
    const float* gamma = (const float*)d_in[3];
    const float* beta  = (const float*)d_in[4];
    const float* W2    = (const float*)d_in[5];
    const float* b2    = (const float*)d_in[6];
    float* out = (float*)d_out;

    float* ws  = (float*)d_ws;
    float* pt  = ws;               // 2048 * 4 floats = 32 KB
    float* wpk = ws + NPTS * 4;    // 32 pairs * 32 floats = 4 KB

    prep_kernel<<<9, 256, 0, stream>>>(rv, W1, b1, gamma, beta, W2, pt, wpk);

    dim3 grid(NN / 256, NN, NB);
    rpe_kernel<<<grid, 256, 0, stream>>>(pt, wpk, b2, out);
}

// Round 4
// 57.975 us; speedup vs baseline: 3.5065x; 1.7986x over previous
//
#include <hip/hip_runtime.h>
#include <math.h>

#define NB 2
#define NN 1024
#define NH 64
#define NK 8

typedef float f32x4 __attribute__((ext_vector_type(4)));
typedef _Float16 half8 __attribute__((ext_vector_type(8)));
typedef _Float16 half2t __attribute__((ext_vector_type(2)));
typedef __fp16 fp16x2 __attribute__((ext_vector_type(2)));

union FragU { uint32_t u[4]; uint4 q; half8 h; };
union H2U  { half2t h; fp16x2 p; uint32_t u; };

static __device__ __forceinline__ uint32_t pk_rne(float a, float b) {
    half2t t; t[0] = (_Float16)a; t[1] = (_Float16)b;
    H2U r; r.h = t; return r.u;
}

// ---------------- prep ----------------
// blocks 0..7   : pt[b][n] = (x, y, cos h, sin h) f32
// blocks 8..519 : Qpack: per (b,i), per h: A1-fragment coefficients (fp16)
//                 k0:cj k1:sj k2:xj k3:yj k4:g0 k5:1  (k6..31 zero)
//                 A-frag layout: lane sl holds row h=16t+sl, k=e (lanes 0-15)
// block 520     : W2pack A2-fragments: row k_out=l&15 (8 real+8 zero),
//                 k(h) = 32s + 8*(l>>4) + e
__global__ void prep_kernel(const float* __restrict__ rv,
                            const float* __restrict__ W1,
                            const float* __restrict__ b1,
                            const float* __restrict__ W2,
                            float* __restrict__ pt,
                            uint4* __restrict__ qpack,
                            uint4* __restrict__ w2pack) {
    const int tid = threadIdx.x;
    const int bid = blockIdx.x;
    if (bid < 8) {
        const int idx = bid * 256 + tid;  // 0..2047
        const float x0 = rv[idx*4+0], y0 = rv[idx*4+1];
        const float vx = rv[idx*4+2] - x0, vy = rv[idx*4+3] - y0;
        const float rinv = rsqrtf(fmaf(vx, vx, vy * vy));
        float4 o; o.x = x0; o.y = y0; o.z = vx * rinv; o.w = vy * rinv;
        reinterpret_cast<float4*>(pt)[idx] = o;
    } else if (bid < 520) {
        __shared__ float mean[6];
        if (tid < 5)       { float m = 0.f; for (int h = 0; h < NH; ++h) m += W1[tid*NH+h]; mean[tid] = m * (1.f/NH); }
        else if (tid == 5) { float m = 0.f; for (int h = 0; h < NH; ++h) m += b1[h];        mean[5]   = m * (1.f/NH); }
        __syncthreads();
        const int gid = (bid - 8) * 256 + tid;     // (b,i,h)
        const int b = gid >> 16, i = (gid >> 6) & 1023, h = gid & 63;
        const float x0 = rv[(b*NN+i)*4+0], y0 = rv[(b*NN+i)*4+1];
        const float vx = rv[(b*NN+i)*4+2] - x0, vy = rv[(b*NN+i)*4+3] - y0;
        const float rinv = rsqrtf(fmaf(vx, vx, vy * vy));
        const float ci = vx * rinv, si = vy * rinv;
        const float w0 = W1[0*NH+h]-mean[0], w1 = W1[1*NH+h]-mean[1], w2 = W1[2*NH+h]-mean[2],
                    w3 = W1[3*NH+h]-mean[3], w4 = W1[4*NH+h]-mean[4];
        const float bb = b1[h] - mean[5];
        const float qc = fmaf(w1, ci,  w2 * si);
        const float qs = fmaf(w1, si, -w2 * ci);
        const float qx = fmaf(-w3, ci,  w4 * si);
        const float qy = fmaf(-w3, si, -w4 * ci);
        const float cn = fmaf(w3, fmaf(x0, ci, y0 * si), fmaf(w4, fmaf(y0, ci, -x0 * si), bb));
        uint4 v;
        v.x = pk_rne(qc, qs); v.y = pk_rne(qx, qy); v.z = pk_rne(w0, cn); v.w = 0u;
        qpack[((b*NN + i)*4 + (h >> 4))*16 + (h & 15)] = v;
    } else {
        if (tid < 128) {
            const int s = tid >> 6, l = tid & 63;
            const int k = l & 15, g = l >> 4;
            uint32_t dw[4];
            for (int e = 0; e < 4; ++e) {
                const int h0 = 32*s + 8*g + 2*e;
                const float a = (k < 8) ? W2[h0*NK + k]     : 0.f;
                const float c = (k < 8) ? W2[(h0+1)*NK + k] : 0.f;
                dw[e] = pk_rne(a, c);
            }
            uint4 v; v.x = dw[0]; v.y = dw[1]; v.z = dw[2]; v.w = dw[3];
            w2pack[s*64 + l] = v;
        }
    }
}

// ---------------- main ----------------
// Per wave: 16 j's (C-cols), loop over 32 i's. GEMM1 swapped (A=Q, B=feat)
// so each lane owns ONE j; LN reduce = 2 shfl_xor; pk-f16 norm; Y through
// 2KB/wave swizzled LDS; GEMM2 vs preloaded W2 frags; half-wave stores.
__global__ __launch_bounds__(256, 4) void rpe_kernel(
    const float* __restrict__ pt,
    const uint4* __restrict__ qpack,
    const uint4* __restrict__ w2pack,
    const float* __restrict__ gamma,
    const float* __restrict__ beta,
    const float* __restrict__ b2,
    float* __restrict__ out) {
    __shared__ unsigned char lds[8192];
    const int tid  = threadIdx.x;
    const int wave = tid >> 6;
    const int lane = tid & 63;
    const int sl   = lane & 15;
    const int g    = lane >> 4;
    const bool act  = lane < 16;
    const bool sact = lane < 32;
    const int b  = blockIdx.z;
    const int j0 = blockIdx.x * 64 + wave * 16;
    const int iBase = blockIdx.y * 32;

    // static feature dwords (B1 k0..3), lanes>=16 must be zero
    const float4 pj = reinterpret_cast<const float4*>(pt)[b*NN + j0 + sl];
    const float xj = pj.x, yj = pj.y;
    const uint32_t d0 = act ? pk_rne(pj.z, pj.w) : 0u;
    const uint32_t d1 = act ? pk_rne(pj.x, pj.y) : 0u;

    // gamma/beta fp16 pairs: index t*2+rr -> h0 = 16t + 4g + 2rr
    half2t gph[8], bph[8];
#pragma unroll
    for (int t = 0; t < 4; ++t)
#pragma unroll
        for (int rr = 0; rr < 2; ++rr) {
            const int h0 = 16*t + 4*g + 2*rr;
            H2U gg, bb2;
            gg.u = pk_rne(gamma[h0], gamma[h0+1]);
            bb2.u = pk_rne(beta[h0],  beta[h0+1]);
            gph[t*2+rr] = gg.h; bph[t*2+rr] = bb2.h;
        }
    // W2 A-fragments (once)
    FragU a2_0, a2_1;
    a2_0.q = w2pack[0*64 + lane];
    a2_1.q = w2pack[1*64 + lane];
    // b2 per-lane (rows k_out = 4g+r; only lanes<32 store)
    float b2v[4];
#pragma unroll
    for (int r = 0; r < 4; ++r) b2v[r] = b2[(4*g + r) & 7];

    // i-invariant LDS addresses (XOR-swizzled; [j=sl][h] fp16, row stride 128B)
    const unsigned wbase = wave * 2048;
    const unsigned swz = (unsigned)((sl & 7) << 4);
    unsigned wyaddr[4], rdaddr[2];
#pragma unroll
    for (int t = 0; t < 4; ++t) wyaddr[t] = wbase + ((((unsigned)sl*128u) + 32u*t + 8u*(unsigned)g) ^ swz);
#pragma unroll
    for (int s = 0; s < 2; ++s) rdaddr[s] = wbase + ((((unsigned)sl*128u) + 64u*s + 16u*(unsigned)g) ^ swz);

    half2t z2; z2[0] = (_Float16)0.f; z2[1] = (_Float16)0.f;

    for (int ii = 0; ii < 32; ++ii) {
        const int i = iBase + ii;
        const float4 pi4 = reinterpret_cast<const float4*>(pt)[b*NN + i];  // uniform

        FragU qf0, qf1, qf2, qf3;
        if (act) {
            const uint4* qp = qpack + ((size_t)(b*NN + i)*4)*16 + sl;
            qf0.q = qp[0]; qf1.q = qp[16]; qf2.q = qp[32]; qf3.q = qp[48];
        } else {
            qf0.q = make_uint4(0,0,0,0); qf1.q = qf0.q; qf2.q = qf0.q; qf3.q = qf0.q;
        }

        const float dx = pi4.x - xj, dy = pi4.y - yj;
        const float dist = sqrtf(fmaf(dx, dx, dy * dy));
        const float g0v = logf(dist + 1e-5f);
        H2U d2u; d2u.p = __builtin_amdgcn_cvt_pkrtz(g0v, 1.0f);
        const uint32_t d2 = act ? d2u.u : 0u;
        FragU bf; bf.u[0] = d0; bf.u[1] = d1; bf.u[2] = d2; bf.u[3] = 0u;

        f32x4 z4 = {0.f, 0.f, 0.f, 0.f};
        f32x4 c1_0 = __builtin_amdgcn_mfma_f32_16x16x32_f16(qf0.h, bf.h, z4, 0, 0, 0);
        f32x4 c1_1 = __builtin_amdgcn_mfma_f32_16x16x32_f16(qf1.h, bf.h, z4, 0, 0, 0);
        f32x4 c1_2 = __builtin_amdgcn_mfma_f32_16x16x32_f16(qf2.h, bf.h, z4, 0, 0, 0);
        f32x4 c1_3 = __builtin_amdgcn_mfma_f32_16x16x32_f16(qf3.h, bf.h, z4, 0, 0, 0);

        // mean over 64 h of this lane's j-column
        float sm = (c1_0.x + c1_0.y + c1_0.z + c1_0.w)
                 + (c1_1.x + c1_1.y + c1_1.z + c1_1.w)
                 + (c1_2.x + c1_2.y + c1_2.z + c1_2.w)
                 + (c1_3.x + c1_3.y + c1_3.z + c1_3.w);
        sm += __shfl_xor(sm, 16);
        sm += __shfl_xor(sm, 32);
        const float mu = sm * (1.f/64.f);
        const f32x4 mu4 = {mu, mu, mu, mu};
        const f32x4 t0 = c1_0 - mu4, t1 = c1_1 - mu4, t2 = c1_2 - mu4, t3 = c1_3 - mu4;

        float vs = t0.x*t0.x + t0.y*t0.y + t0.z*t0.z + t0.w*t0.w
                 + t1.x*t1.x + t1.y*t1.y + t1.z*t1.z + t1.w*t1.w
                 + t2.x*t2.x + t2.y*t2.y + t2.z*t2.z + t2.w*t2.w
                 + t3.x*t3.x + t3.y*t3.y + t3.z*t3.z + t3.w*t3.w;
        vs += __shfl_xor(vs, 16);
        vs += __shfl_xor(vs, 32);
        const float inv = rsqrtf(fmaf(vs, 1.f/64.f, 1e-5f));
        H2U inv2u; inv2u.p = __builtin_amdgcn_cvt_pkrtz(inv, inv);
        const half2t inv2 = inv2u.h;

#define DO_TILE(T, TC) { \
        H2U p0_, p1_; \
        p0_.p = __builtin_amdgcn_cvt_pkrtz(TC.x, TC.y); \
        p1_.p = __builtin_amdgcn_cvt_pkrtz(TC.z, TC.w); \
        half2t u0_ = p0_.h * inv2, u1_ = p1_.h * inv2; \
        half2t y0_ = __builtin_elementwise_fma(u0_, gph[T*2+0], bph[T*2+0]); \
        half2t y1_ = __builtin_elementwise_fma(u1_, gph[T*2+1], bph[T*2+1]); \
        y0_ = __builtin_elementwise_max(y0_, z2); \
        y1_ = __builtin_elementwise_max(y1_, z2); \
        H2U o0_, o1_; o0_.h = y0_; o1_.h = y1_; \
        uint2 wv_; wv_.x = o0_.u; wv_.y = o1_.u; \
        *reinterpret_cast<uint2*>(lds + wyaddr[T]) = wv_; }

        DO_TILE(0, t0)
        DO_TILE(1, t1)
        DO_TILE(2, t2)
        DO_TILE(3, t3)
#undef DO_TILE

        FragU yb0, yb1;
        yb0.q = *reinterpret_cast<const uint4*>(lds + rdaddr[0]);
        yb1.q = *reinterpret_cast<const uint4*>(lds + rdaddr[1]);
        f32x4 c2 = __builtin_amdgcn_mfma_f32_16x16x32_f16(a2_0.h, yb0.h, z4, 0, 0, 0);
        c2 = __builtin_amdgcn_mfma_f32_16x16x32_f16(a2_1.h, yb1.h, c2, 0, 0, 0);

        if (sact) {
            const size_t plane = (size_t)NN * NN;
            const size_t base = ((size_t)(b*NK + 4*g) * NN + i) * NN + j0 + sl;
            out[base]             = c2.x + b2v[0];
            out[base + plane]     = c2.y + b2v[1];
            out[base + 2*plane]   = c2.z + b2v[2];
            out[base + 3*plane]   = c2.w + b2v[3];
        }
    }
}

extern "C" void kernel_launch(void* const* d_in, const int* in_sizes, int n_in,
                              void* d_out, int out_size, void* d_ws, size_t ws_size,
                              hipStream_t stream) {
    const float* rv    = (const float*)d_in[0];
    const float* W1    = (const float*)d_in[1];
    const float* b1    = (const float*)d_in[2];
    const float* gamma = (const float*)d_in[3];
    const float* beta  = (const float*)d_in[4];
    const float* W2    = (const float*)d_in[5];
    const float* b2    = (const float*)d_in[6];
    float* out = (float*)d_out;

    float* ws = (float*)d_ws;
    float* pt      = ws;                                  // 2048*4 f32 = 32 KB
    uint4* qpack   = (uint4*)(ws + 8192);                 // 2 MB
    uint4* w2pack  = (uint4*)(ws + 8192 + 524288);        // 2 KB

    prep_kernel<<<521, 256, 0, stream>>>(rv, W1, b1, W2, pt, qpack, w2pack);

    dim3 grid(NN / 64, NN / 32, NB);
    rpe_kernel<<<grid, 256, 0, stream>>>(pt, qpack, w2pack, gamma, beta, b2, out);
}

// Round 5
// 43.324 us; speedup vs baseline: 4.6923x; 1.3382x over previous
//
#include <hip/hip_runtime.h>
#include <math.h>

#define NB 2
#define NN 1024
#define NH 64
#define NK 8

typedef float f32x2 __attribute__((ext_vector_type(2)));
typedef float f32x4 __attribute__((ext_vector_type(4)));
typedef float f32x16 __attribute__((ext_vector_type(16)));
typedef _Float16 half8 __attribute__((ext_vector_type(8)));
typedef _Float16 half2t __attribute__((ext_vector_type(2)));
typedef __fp16 fp16x2 __attribute__((ext_vector_type(2)));

union FragU { uint32_t u[4]; uint4 q; half8 h; };
union H2U  { half2t h; fp16x2 p; uint32_t u; };
union C32U { f32x16 v; f32x2 d[8]; float f[16]; };

static __device__ __forceinline__ uint32_t pk_rne(float a, float b) {
    half2t t; t[0] = (_Float16)a; t[1] = (_Float16)b;
    H2U r; r.h = t; return r.u;
}

// ---------------- prep ----------------
// blocks 0..7   : pt[b][n] = (x, y, cos h, sin h) f32
// blocks 8..519 : qpack A1-frags for 32x32x16: per (b,i), tile T=h>>5,
//                 lane slot h&31 holds 16B: w0=(qc,qs) w1=(qx,qy) w2=(w0f,cn) w3=0
// block 520     : w2pack A2-frags (16x16x32): row k_out=l&15, h=32s+8*(l>>4)+e
__global__ void prep_kernel(const float* __restrict__ rv,
                            const float* __restrict__ W1,
                            const float* __restrict__ b1,
                            const float* __restrict__ W2,
                            float* __restrict__ pt,
                            uint4* __restrict__ qpack,
                            uint4* __restrict__ w2pack) {
    const int tid = threadIdx.x;
    const int bid = blockIdx.x;
    if (bid < 8) {
        const int idx = bid * 256 + tid;  // 0..2047
        const float x0 = rv[idx*4+0], y0 = rv[idx*4+1];
        const float vx = rv[idx*4+2] - x0, vy = rv[idx*4+3] - y0;
        const float rinv = rsqrtf(fmaf(vx, vx, vy * vy));
        float4 o; o.x = x0; o.y = y0; o.z = vx * rinv; o.w = vy * rinv;
        reinterpret_cast<float4*>(pt)[idx] = o;
    } else if (bid < 520) {
        __shared__ float mean[6];
        if (tid < 5)       { float m = 0.f; for (int h = 0; h < NH; ++h) m += W1[tid*NH+h]; mean[tid] = m * (1.f/NH); }
        else if (tid == 5) { float m = 0.f; for (int h = 0; h < NH; ++h) m += b1[h];        mean[5]   = m * (1.f/NH); }
        __syncthreads();
        const int gid = (bid - 8) * 256 + tid;     // (b,i,h)
        const int b = gid >> 16, i = (gid >> 6) & 1023, h = gid & 63;
        const float x0 = rv[(b*NN+i)*4+0], y0 = rv[(b*NN+i)*4+1];
        const float vx = rv[(b*NN+i)*4+2] - x0, vy = rv[(b*NN+i)*4+3] - y0;
        const float rinv = rsqrtf(fmaf(vx, vx, vy * vy));
        const float ci = vx * rinv, si = vy * rinv;
        const float w0 = W1[0*NH+h]-mean[0], w1 = W1[1*NH+h]-mean[1], w2 = W1[2*NH+h]-mean[2],
                    w3 = W1[3*NH+h]-mean[3], w4 = W1[4*NH+h]-mean[4];
        const float bb = b1[h] - mean[5];
        const float qc = fmaf(w1, ci,  w2 * si);
        const float qs = fmaf(w1, si, -w2 * ci);
        const float qx = fmaf(-w3, ci,  w4 * si);
        const float qy = fmaf(-w3, si, -w4 * ci);
        const float cn = fmaf(w3, fmaf(x0, ci, y0 * si), fmaf(w4, fmaf(y0, ci, -x0 * si), bb));
        uint4 v;
        v.x = pk_rne(qc, qs); v.y = pk_rne(qx, qy); v.z = pk_rne(w0, cn); v.w = 0u;
        qpack[((size_t)(b*NN + i)*2 + (h >> 5))*32 + (h & 31)] = v;
    } else {
        if (tid < 128) {
            const int s = tid >> 6, l = tid & 63;
            const int k = l & 15, g = l >> 4;
            uint32_t dw[4];
            for (int e = 0; e < 4; ++e) {
                const int h0 = 32*s + 8*g + 2*e;
                const float a = (k < 8) ? W2[h0*NK + k]     : 0.f;
                const float c = (k < 8) ? W2[(h0+1)*NK + k] : 0.f;
                dw[e] = pk_rne(a, c);
            }
            uint4 v; v.x = dw[0]; v.y = dw[1]; v.z = dw[2]; v.w = dw[3];
            w2pack[s*64 + l] = v;
        }
    }
}

// ---------------- main ----------------
// Per wave: 32 j's (cols of 32x32 MFMA), loop over 16 i's.
// GEMM1: 2x mfma_32x32x16_f16 (A=Q frags, B=features, K=16 w/ 6 real).
// LN: E[x2]-mu^2, pk_f32 trees + 1 shfl_xor(32). Normalize packed f16.
// Y -> conflict-free swizzled LDS -> 4x mfma_16x16x32 vs W2 frags.
__global__ __launch_bounds__(256, 4) void rpe_kernel(
    const float* __restrict__ pt,
    const uint4* __restrict__ qpack,
    const uint4* __restrict__ w2pack,
    const float* __restrict__ gamma,
    const float* __restrict__ beta,
    const float* __restrict__ b2,
    float* __restrict__ out) {
    __shared__ unsigned char lds[16384];
    const int tid  = threadIdx.x;
    const int wave = tid >> 6;
    const int lane = tid & 63;
    const int jj   = lane & 31;
    const int hi   = lane >> 5;
    const int sl   = lane & 15;
    const int g4   = lane >> 4;        // 0..3
    const int b  = blockIdx.z;
    const int j0 = blockIdx.x * 128 + wave * 32;
    const int iBase = blockIdx.y * 16;

    const uint32_t hm = hi ? 0u : 0xFFFFFFFFu;

    const float4 pj = reinterpret_cast<const float4*>(pt)[b*NN + j0 + jj];
    const float xj = pj.x, yj = pj.y;
    const uint32_t d0 = pk_rne(pj.z, pj.w) & hm;
    const uint32_t d1 = pk_rne(xj, yj) & hm;

    // gamma/beta fp16 pairs: word (T,m) -> rows h0,h0+1 ; h0 = 32T+8(m>>1)+2(m&1)+4hi
    uint32_t gph[16], bph[16];
#pragma unroll
    for (int T = 0; T < 2; ++T)
#pragma unroll
        for (int m = 0; m < 8; ++m) {
            const int h0 = 32*T + 8*(m>>1) + 2*(m&1) + 4*hi;
            gph[T*8+m] = pk_rne(gamma[h0], gamma[h0+1]);
            bph[T*8+m] = pk_rne(beta[h0],  beta[h0+1]);
        }

    FragU a2_0, a2_1;
    a2_0.q = w2pack[lane];
    a2_1.q = w2pack[64 + lane];
    float b2v[4];
#pragma unroll
    for (int r = 0; r < 4; ++r) b2v[r] = b2[(4*g4 + r) & 7];

    // LDS layout per wave: [j][h] f16, row stride 128B, swizzle: low7 ^= (j&7)<<4
    const unsigned wbase = wave * 4096u;
    const unsigned swzw = (unsigned)((jj & 7) << 4);
    unsigned wr[8];
#pragma unroll
    for (int T = 0; T < 2; ++T)
#pragma unroll
        for (int p = 0; p < 4; ++p)
            wr[T*4+p] = wbase + (unsigned)jj*128u + (((unsigned)(64*T + 16*p + 8*hi)) ^ swzw);
    unsigned rd[4];
#pragma unroll
    for (int J = 0; J < 2; ++J)
#pragma unroll
        for (int c = 0; c < 2; ++c) {
            const int jr = 16*J + sl;
            rd[J*2+c] = wbase + (unsigned)jr*128u + (((unsigned)(64*c + 16*g4)) ^ ((unsigned)((jr&7)<<4)));
        }

    const uint4* qrow = qpack + (size_t)(b*NN + iBase) * 64;
    const float4* ptb = reinterpret_cast<const float4*>(pt) + b*NN + iBase;

    uint4 qA = qrow[jj];
    uint4 qB = qrow[32 + jj];
    float4 piv = ptb[0];

    const f32x16 z16 = {0,0,0,0,0,0,0,0,0,0,0,0,0,0,0,0};
    const f32x4 z4 = {0,0,0,0};
    half2t z2; z2[0] = (_Float16)0.f; z2[1] = (_Float16)0.f;
    const size_t plane = (size_t)NN * NN;

    for (int ii = 0; ii < 16; ++ii) {
        const int i = iBase + ii;
        FragU qf0, qf1;
        qf0.u[0] = qA.x & hm; qf0.u[1] = qA.y & hm; qf0.u[2] = qA.z & hm; qf0.u[3] = 0u;
        qf1.u[0] = qB.x & hm; qf1.u[1] = qB.y & hm; qf1.u[2] = qB.z & hm; qf1.u[3] = 0u;
        const float pix = piv.x, piy = piv.y;
        const int nx = (ii < 15) ? (ii + 1) : 15;
        qA = qrow[nx*64 + jj];
        qB = qrow[nx*64 + 32 + jj];
        piv = ptb[nx];

        const float dx = pix - xj, dy = piy - yj;
        const float g0v = logf(sqrtf(fmaf(dx, dx, dy * dy)) + 1e-5f);
        H2U d2u; d2u.p = __builtin_amdgcn_cvt_pkrtz(g0v, 1.0f);
        FragU bf; bf.u[0] = d0; bf.u[1] = d1; bf.u[2] = d2u.u & hm; bf.u[3] = 0u;

        C32U cA, cB;
        cA.v = __builtin_amdgcn_mfma_f32_32x32x16_f16(qf0.h, bf.h, z16, 0, 0, 0);
        cB.v = __builtin_amdgcn_mfma_f32_32x32x16_f16(qf1.h, bf.h, z16, 0, 0, 0);

        // sum tree (pk f32)
        f32x2 s0 = cA.d[0] + cA.d[1], s1 = cA.d[2] + cA.d[3];
        f32x2 s2 = cA.d[4] + cA.d[5], s3 = cA.d[6] + cA.d[7];
        f32x2 s4 = cB.d[0] + cB.d[1], s5 = cB.d[2] + cB.d[3];
        f32x2 s6 = cB.d[4] + cB.d[5], s7 = cB.d[6] + cB.d[7];
        s0 += s1; s2 += s3; s4 += s5; s6 += s7;
        s0 += s2; s4 += s6; s0 += s4;
        float sm = s0[0] + s0[1];
        // sumsq tree (pk f32, 4 accumulators)
        f32x2 q0 = cA.d[0]*cA.d[0], q1 = cA.d[1]*cA.d[1], q2 = cA.d[2]*cA.d[2], q3 = cA.d[3]*cA.d[3];
        q0 = __builtin_elementwise_fma(cA.d[4], cA.d[4], q0);
        q1 = __builtin_elementwise_fma(cA.d[5], cA.d[5], q1);
        q2 = __builtin_elementwise_fma(cA.d[6], cA.d[6], q2);
        q3 = __builtin_elementwise_fma(cA.d[7], cA.d[7], q3);
        q0 = __builtin_elementwise_fma(cB.d[0], cB.d[0], q0);
        q1 = __builtin_elementwise_fma(cB.d[1], cB.d[1], q1);
        q2 = __builtin_elementwise_fma(cB.d[2], cB.d[2], q2);
        q3 = __builtin_elementwise_fma(cB.d[3], cB.d[3], q3);
        q0 = __builtin_elementwise_fma(cB.d[4], cB.d[4], q0);
        q1 = __builtin_elementwise_fma(cB.d[5], cB.d[5], q1);
        q2 = __builtin_elementwise_fma(cB.d[6], cB.d[6], q2);
        q3 = __builtin_elementwise_fma(cB.d[7], cB.d[7], q3);
        q0 += q1; q2 += q3; q0 += q2;
        float sq = q0[0] + q0[1];

        sm += __shfl_xor(sm, 32);
        sq += __shfl_xor(sq, 32);
        const float mu  = sm * (1.f/64.f);
        const float ex2 = sq * (1.f/64.f);
        const float inv = rsqrtf(fmaf(-mu, mu, ex2) + 1e-5f);
        const float nmi = -mu * inv;
        const f32x2 inv2 = {inv, inv}, nmi2 = {nmi, nmi};

        uint32_t yw[8];
#pragma unroll
        for (int m = 0; m < 8; ++m) {
            f32x2 t = __builtin_elementwise_fma(cA.d[m], inv2, nmi2);
            H2U ph; ph.p = __builtin_amdgcn_cvt_pkrtz(t[0], t[1]);
            H2U gg, bb; gg.u = gph[m]; bb.u = bph[m];
            half2t y = __builtin_elementwise_fma(ph.h, gg.h, bb.h);
            y = __builtin_elementwise_max(y, z2);
            H2U o; o.h = y; yw[m] = o.u;
        }
#pragma unroll
        for (int p = 0; p < 4; ++p) {
            uint2 wv; wv.x = yw[2*p]; wv.y = yw[2*p+1];
            *reinterpret_cast<uint2*>(lds + wr[p]) = wv;
        }
#pragma unroll
        for (int m = 0; m < 8; ++m) {
            f32x2 t = __builtin_elementwise_fma(cB.d[m], inv2, nmi2);
            H2U ph; ph.p = __builtin_amdgcn_cvt_pkrtz(t[0], t[1]);
            H2U gg, bb; gg.u = gph[8+m]; bb.u = bph[8+m];
            half2t y = __builtin_elementwise_fma(ph.h, gg.h, bb.h);
            y = __builtin_elementwise_max(y, z2);
            H2U o; o.h = y; yw[m] = o.u;
        }
#pragma unroll
        for (int p = 0; p < 4; ++p) {
            uint2 wv; wv.x = yw[2*p]; wv.y = yw[2*p+1];
            *reinterpret_cast<uint2*>(lds + wr[4+p]) = wv;
        }

        FragU y00, y01, y10, y11;
        y00.q = *reinterpret_cast<const uint4*>(lds + rd[0]);
        y01.q = *reinterpret_cast<const uint4*>(lds + rd[1]);
        y10.q = *reinterpret_cast<const uint4*>(lds + rd[2]);
        y11.q = *reinterpret_cast<const uint4*>(lds + rd[3]);
        f32x4 c20 = __builtin_amdgcn_mfma_f32_16x16x32_f16(a2_0.h, y00.h, z4, 0, 0, 0);
        c20 = __builtin_amdgcn_mfma_f32_16x16x32_f16(a2_1.h, y01.h, c20, 0, 0, 0);
        f32x4 c21 = __builtin_amdgcn_mfma_f32_16x16x32_f16(a2_0.h, y10.h, z4, 0, 0, 0);
        c21 = __builtin_amdgcn_mfma_f32_16x16x32_f16(a2_1.h, y11.h, c21, 0, 0, 0);

        if (lane < 32) {
            const size_t base = ((size_t)(b*NK + 4*g4)) * plane + (size_t)i * NN + j0 + sl;
            out[base]           = c20.x + b2v[0];
            out[base +   plane] = c20.y + b2v[1];
            out[base + 2*plane] = c20.z + b2v[2];
            out[base + 3*plane] = c20.w + b2v[3];
            out[base + 16]           = c21.x + b2v[0];
            out[base + 16 +   plane] = c21.y + b2v[1];
            out[base + 16 + 2*plane] = c21.z + b2v[2];
            out[base + 16 + 3*plane] = c21.w + b2v[3];
        }
    }
}

extern "C" void kernel_launch(void* const* d_in, const int* in_sizes, int n_in,
                              void* d_out, int out_size, void* d_ws, size_t ws_size,
                              hipStream_t stream) {
    const float* rv    = (const float*)d_in[0];
    const float* W1    = (const float*)d_in[1];
    const float* b1    = (const float*)d_in[2];
    const float* gamma = (const float*)d_in[3];
    const float* beta  = (const float*)d_in[4];
    const float* W2    = (const float*)d_in[5];
    const float* b2    = (const float*)d_in[6];
    float* out = (float*)d_out;

    float* ws = (float*)d_ws;
    float* pt      = ws;                                  // 2048*4 f32 = 32 KB
    uint4* qpack   = (uint4*)(ws + 8192);                 // 2 MB
    uint4* w2pack  = (uint4*)(ws + 8192 + 524288);        // 2 KB

    prep_kernel<<<521, 256, 0, stream>>>(rv, W1, b1, W2, pt, qpack, w2pack);

    dim3 grid(NN / 128, NN / 16, NB);
    rpe_kernel<<<grid, 256, 0, stream>>>(pt, qpack, w2pack, gamma, beta, b2, out);
}

// Round 6
// 40.066 us; speedup vs baseline: 5.0738x; 1.0813x over previous
//
#include <hip/hip_runtime.h>
#include <math.h>

#define NB 2
#define NN 1024
#define NH 64
#define NK 8
#define ITILE 8

typedef float f32x2 __attribute__((ext_vector_type(2)));
typedef float f32x4 __attribute__((ext_vector_type(4)));
typedef float f32x16 __attribute__((ext_vector_type(16)));
typedef _Float16 half8 __attribute__((ext_vector_type(8)));
typedef _Float16 half2t __attribute__((ext_vector_type(2)));
typedef __fp16 fp16x2 __attribute__((ext_vector_type(2)));

union FragU { uint32_t u[4]; uint4 q; half8 h; };
union H2U  { half2t h; fp16x2 p; uint32_t u; };
union C32U { f32x16 v; f32x2 d[8]; float f[16]; };

static __device__ __forceinline__ uint32_t pk_rne(float a, float b) {
    half2t t; t[0] = (_Float16)a; t[1] = (_Float16)b;
    H2U r; r.h = t; return r.u;
}

// ---------------- prep ----------------
// blocks 0..7   : pt[b][n] = (x, y, cos h, sin h) f32
// blocks 8..519 : qpack A1-frags (32x32x16), 64 lane-slots per (b,i,tile):
//                 slot h&31 = 16B {(qc,qs),(qx,qy),(w0,cn),0}; slots 32..63 = 0
//                 (hi-lanes read zeros -> no masking in main loop)
// block 520     : w2pack A2-frags (16x16x32): row k_out=l&15, h=32s+8*(l>>4)+e
__global__ void prep_kernel(const float* __restrict__ rv,
                            const float* __restrict__ W1,
                            const float* __restrict__ b1,
                            const float* __restrict__ W2,
                            float* __restrict__ pt,
                            uint4* __restrict__ qpack,
                            uint4* __restrict__ w2pack) {
    const int tid = threadIdx.x;
    const int bid = blockIdx.x;
    if (bid < 8) {
        const int idx = bid * 256 + tid;  // 0..2047
        const float x0 = rv[idx*4+0], y0 = rv[idx*4+1];
        const float vx = rv[idx*4+2] - x0, vy = rv[idx*4+3] - y0;
        const float rinv = rsqrtf(fmaf(vx, vx, vy * vy));
        float4 o; o.x = x0; o.y = y0; o.z = vx * rinv; o.w = vy * rinv;
        reinterpret_cast<float4*>(pt)[idx] = o;
    } else if (bid < 520) {
        __shared__ float mean[6];
        if (tid < 5)       { float m = 0.f; for (int h = 0; h < NH; ++h) m += W1[tid*NH+h]; mean[tid] = m * (1.f/NH); }
        else if (tid == 5) { float m = 0.f; for (int h = 0; h < NH; ++h) m += b1[h];        mean[5]   = m * (1.f/NH); }
        __syncthreads();
        const int gid = (bid - 8) * 256 + tid;     // (b,i,h)
        const int b = gid >> 16, i = (gid >> 6) & 1023, h = gid & 63;
        const float x0 = rv[(b*NN+i)*4+0], y0 = rv[(b*NN+i)*4+1];
        const float vx = rv[(b*NN+i)*4+2] - x0, vy = rv[(b*NN+i)*4+3] - y0;
        const float rinv = rsqrtf(fmaf(vx, vx, vy * vy));
        const float ci = vx * rinv, si = vy * rinv;
        const float w0 = W1[0*NH+h]-mean[0], w1 = W1[1*NH+h]-mean[1], w2 = W1[2*NH+h]-mean[2],
                    w3 = W1[3*NH+h]-mean[3], w4 = W1[4*NH+h]-mean[4];
        const float bb = b1[h] - mean[5];
        const float qc = fmaf(w1, ci,  w2 * si);
        const float qs = fmaf(w1, si, -w2 * ci);
        const float qx = fmaf(-w3, ci,  w4 * si);
        const float qy = fmaf(-w3, si, -w4 * ci);
        const float cn = fmaf(w3, fmaf(x0, ci, y0 * si), fmaf(w4, fmaf(y0, ci, -x0 * si), bb));
        uint4 v;
        v.x = pk_rne(qc, qs); v.y = pk_rne(qx, qy); v.z = pk_rne(w0, cn); v.w = 0u;
        const size_t qb = ((size_t)(b*NN + i)*2 + (h >> 5))*64 + (h & 31);
        qpack[qb] = v;
        qpack[qb + 32] = make_uint4(0,0,0,0);
    } else {
        if (tid < 128) {
            const int s = tid >> 6, l = tid & 63;
            const int k = l & 15, g = l >> 4;
            uint32_t dw[4];
            for (int e = 0; e < 4; ++e) {
                const int h0 = 32*s + 8*g + 2*e;
                const float a = (k < 8) ? W2[h0*NK + k]     : 0.f;
                const float c = (k < 8) ? W2[(h0+1)*NK + k] : 0.f;
                dw[e] = pk_rne(a, c);
            }
            uint4 v; v.x = dw[0]; v.y = dw[1]; v.z = dw[2]; v.w = dw[3];
            w2pack[s*64 + l] = v;
        }
    }
}

// ---------------- main ----------------
// Per wave: 32 j, 8 i. GEMM1 2x mfma_32x32x16. LN with mu==0 (exact by
// W1 pre-centering): inv = rsqrt(E[x^2]+eps), no sum tree, 1 shfl.
// f16 normalize (mul inv, fma gamma/beta, max). GEMM2 software-pipelined:
// iter ii does MFMA2+store for i-1 (y-frags read end of prev iter from
// double-buffered LDS), hiding LDS latency under MFMA1/LN.
__global__ __launch_bounds__(256, 3) void rpe_kernel(
    const float* __restrict__ pt,
    const uint4* __restrict__ qpack,
    const uint4* __restrict__ w2pack,
    const float* __restrict__ gamma,
    const float* __restrict__ beta,
    const float* __restrict__ b2,
    float* __restrict__ out) {
    __shared__ unsigned char lds[32768];
    const int tid  = threadIdx.x;
    const int wave = tid >> 6;
    const int lane = tid & 63;
    const int jj   = lane & 31;
    const int hi   = lane >> 5;
    const int sl   = lane & 15;
    const int g4   = lane >> 4;        // 0..3
    const int b  = blockIdx.z;
    const int j0 = blockIdx.x * 128 + wave * 32;
    const int iBase = blockIdx.y * ITILE;

    const uint32_t hm = hi ? 0u : 0xFFFFFFFFu;

    const float4 pj = reinterpret_cast<const float4*>(pt)[b*NN + j0 + jj];
    const float xj = pj.x, yj = pj.y;
    const uint32_t d0 = pk_rne(pj.z, pj.w) & hm;
    const uint32_t d1 = pk_rne(xj, yj) & hm;

    // gamma/beta fp16 pairs: word (T,m) -> rows h0,h0+1 ; h0 = 32T+8(m>>1)+2(m&1)+4hi
    uint32_t gph[16], bph[16];
#pragma unroll
    for (int T = 0; T < 2; ++T)
#pragma unroll
        for (int m = 0; m < 8; ++m) {
            const int h0 = 32*T + 8*(m>>1) + 2*(m&1) + 4*hi;
            gph[T*8+m] = pk_rne(gamma[h0], gamma[h0+1]);
            bph[T*8+m] = pk_rne(beta[h0],  beta[h0+1]);
        }

    FragU a2_0, a2_1;
    a2_0.q = w2pack[lane];
    a2_1.q = w2pack[64 + lane];
    float b2v[4];
#pragma unroll
    for (int r = 0; r < 4; ++r) b2v[r] = b2[(4*g4 + r) & 7];

    // LDS per wave: 2 buffers x 4KB; [j][h] f16 rows of 128B, low7 ^= (j&7)<<4
    const unsigned wbase = wave * 8192u;
    const unsigned swzw = (unsigned)((jj & 7) << 4);
    unsigned wr[8];
#pragma unroll
    for (int T = 0; T < 2; ++T)
#pragma unroll
        for (int p = 0; p < 4; ++p)
            wr[T*4+p] = wbase + (unsigned)jj*128u + (((unsigned)(64*T + 16*p + 8*hi)) ^ swzw);
    unsigned rd[4];
#pragma unroll
    for (int J = 0; J < 2; ++J)
#pragma unroll
        for (int c = 0; c < 2; ++c) {
            const int jr = 16*J + sl;
            rd[J*2+c] = wbase + (unsigned)jr*128u + (((unsigned)(64*c + 16*g4)) ^ ((unsigned)((jr&7)<<4)));
        }

    const uint4* qrow = qpack + (size_t)(b*NN + iBase) * 128;
    const float4* ptb = reinterpret_cast<const float4*>(pt) + b*NN + iBase;

    uint4 qA = qrow[lane];
    uint4 qB = qrow[64 + lane];
    float4 piv = ptb[0];

    const f32x16 z16 = {0,0,0,0,0,0,0,0,0,0,0,0,0,0,0,0};
    const f32x4 z4 = {0,0,0,0};
    half2t z2; z2[0] = (_Float16)0.f; z2[1] = (_Float16)0.f;
    const size_t plane = (size_t)NN * NN;

    FragU y00, y01, y10, y11;   // pipelined GEMM2 inputs (read end of prev iter)

    for (int ii = 0; ii < ITILE; ++ii) {
        FragU qf0, qf1;
        qf0.q = qA; qf1.q = qB;
        const float pix = piv.x, piy = piv.y;
        const int nx = (ii < ITILE-1) ? (ii + 1) : (ITILE-1);
        qA = qrow[nx*128 + lane];
        qB = qrow[nx*128 + 64 + lane];
        piv = ptb[nx];

        const float dx = pix - xj, dy = piy - yj;
        const float g0v = logf(sqrtf(fmaf(dx, dx, dy * dy)) + 1e-5f);
        H2U d2u; d2u.p = __builtin_amdgcn_cvt_pkrtz(g0v, 1.0f);
        FragU bf; bf.u[0] = d0; bf.u[1] = d1; bf.u[2] = d2u.u & hm; bf.u[3] = 0u;

        C32U cA, cB;
        cA.v = __builtin_amdgcn_mfma_f32_32x32x16_f16(qf0.h, bf.h, z16, 0, 0, 0);
        cB.v = __builtin_amdgcn_mfma_f32_32x32x16_f16(qf1.h, bf.h, z16, 0, 0, 0);

        // sumsq (mu == 0 exactly by pre-centering) + early cvt to f16
        uint32_t xw[16];
        f32x2 q0 = cA.d[0]*cA.d[0], q1 = cA.d[1]*cA.d[1], q2 = cA.d[2]*cA.d[2], q3 = cA.d[3]*cA.d[3];
        q0 = __builtin_elementwise_fma(cA.d[4], cA.d[4], q0);
        q1 = __builtin_elementwise_fma(cA.d[5], cA.d[5], q1);
        q2 = __builtin_elementwise_fma(cA.d[6], cA.d[6], q2);
        q3 = __builtin_elementwise_fma(cA.d[7], cA.d[7], q3);
#pragma unroll
        for (int m = 0; m < 8; ++m) {
            H2U t; t.p = __builtin_amdgcn_cvt_pkrtz(cA.d[m][0], cA.d[m][1]);
            xw[m] = t.u;
        }
        q0 = __builtin_elementwise_fma(cB.d[0], cB.d[0], q0);
        q1 = __builtin_elementwise_fma(cB.d[1], cB.d[1], q1);
        q2 = __builtin_elementwise_fma(cB.d[2], cB.d[2], q2);
        q3 = __builtin_elementwise_fma(cB.d[3], cB.d[3], q3);
        q0 = __builtin_elementwise_fma(cB.d[4], cB.d[4], q0);
        q1 = __builtin_elementwise_fma(cB.d[5], cB.d[5], q1);
        q2 = __builtin_elementwise_fma(cB.d[6], cB.d[6], q2);
        q3 = __builtin_elementwise_fma(cB.d[7], cB.d[7], q3);
#pragma unroll
        for (int m = 0; m < 8; ++m) {
            H2U t; t.p = __builtin_amdgcn_cvt_pkrtz(cB.d[m][0], cB.d[m][1]);
            xw[8+m] = t.u;
        }
        q0 += q1; q2 += q3; q0 += q2;
        float sq = q0[0] + q0[1];
        sq += __shfl_xor(sq, 32);
        const float inv = rsqrtf(fmaf(sq, 1.f/64.f, 1e-5f));
        H2U inv2u; inv2u.p = __builtin_amdgcn_cvt_pkrtz(inv, inv);
        const half2t inv2 = inv2u.h;

        const unsigned bufo = (unsigned)(ii & 1) * 4096u;
        uint32_t yw[16];
#pragma unroll
        for (int m = 0; m < 16; ++m) {
            H2U x; x.u = xw[m];
            half2t xh = x.h * inv2;
            H2U gg, bb; gg.u = gph[m]; bb.u = bph[m];
            half2t y = __builtin_elementwise_fma(xh, gg.h, bb.h);
            y = __builtin_elementwise_max(y, z2);
            H2U o; o.h = y; yw[m] = o.u;
        }
#pragma unroll
        for (int p = 0; p < 8; ++p) {
            uint2 wv; wv.x = yw[2*p]; wv.y = yw[2*p+1];
            *reinterpret_cast<uint2*>(lds + (wr[p] + bufo)) = wv;
        }

        if (ii) {  // GEMM2 + store for previous i (y-frags loaded last iter)
            f32x4 c20 = __builtin_amdgcn_mfma_f32_16x16x32_f16(a2_0.h, y00.h, z4, 0, 0, 0);
            c20 = __builtin_amdgcn_mfma_f32_16x16x32_f16(a2_1.h, y01.h, c20, 0, 0, 0);
            f32x4 c21 = __builtin_amdgcn_mfma_f32_16x16x32_f16(a2_0.h, y10.h, z4, 0, 0, 0);
            c21 = __builtin_amdgcn_mfma_f32_16x16x32_f16(a2_1.h, y11.h, c21, 0, 0, 0);
            if (lane < 32) {
                const int ip = iBase + ii - 1;
                const size_t base = ((size_t)(b*NK + 4*g4)) * plane + (size_t)ip * NN + j0 + sl;
                out[base]           = c20.x + b2v[0];
                out[base +   plane] = c20.y + b2v[1];
                out[base + 2*plane] = c20.z + b2v[2];
                out[base + 3*plane] = c20.w + b2v[3];
                out[base + 16]           = c21.x + b2v[0];
                out[base + 16 +   plane] = c21.y + b2v[1];
                out[base + 16 + 2*plane] = c21.z + b2v[2];
                out[base + 16 + 3*plane] = c21.w + b2v[3];
            }
        }
        // issue reads for this iter's Y (consumed next iter; DS in-order per wave)
        y00.q = *reinterpret_cast<const uint4*>(lds + (rd[0] + bufo));
        y01.q = *reinterpret_cast<const uint4*>(lds + (rd[1] + bufo));
        y10.q = *reinterpret_cast<const uint4*>(lds + (rd[2] + bufo));
        y11.q = *reinterpret_cast<const uint4*>(lds + (rd[3] + bufo));
    }

    // epilogue: GEMM2 + store for last i
    {
        f32x4 c20 = __builtin_amdgcn_mfma_f32_16x16x32_f16(a2_0.h, y00.h, z4, 0, 0, 0);
        c20 = __builtin_amdgcn_mfma_f32_16x16x32_f16(a2_1.h, y01.h, c20, 0, 0, 0);
        f32x4 c21 = __builtin_amdgcn_mfma_f32_16x16x32_f16(a2_0.h, y10.h, z4, 0, 0, 0);
        c21 = __builtin_amdgcn_mfma_f32_16x16x32_f16(a2_1.h, y11.h, c21, 0, 0, 0);
        if (lane < 32) {
            const int ip = iBase + ITILE - 1;
            const size_t base = ((size_t)(b*NK + 4*g4)) * plane + (size_t)ip * NN + j0 + sl;
            out[base]           = c20.x + b2v[0];
            out[base +   plane] = c20.y + b2v[1];
            out[base + 2*plane] = c20.z + b2v[2];
            out[base + 3*plane] = c20.w + b2v[3];
            out[base + 16]           = c21.x + b2v[0];
            out[base + 16 +   plane] = c21.y + b2v[1];
            out[base + 16 + 2*plane] = c21.z + b2v[2];
            out[base + 16 + 3*plane] = c21.w + b2v[3];
        }
    }
}

extern "C" void kernel_launch(void* const* d_in, const int* in_sizes, int n_in,
                              void* d_out, int out_size, void* d_ws, size_t ws_size,
                              hipStream_t stream) {
    const float* rv    = (const float*)d_in[0];
    const float* W1    = (const float*)d_in[1];
    const float* b1    = (const float*)d_in[2];
    const float* gamma = (const float*)d_in[3];
    const float* beta  = (const float*)d_in[4];
    const float* W2    = (const float*)d_in[5];
    const float* b2    = (const float*)d_in[6];
    float* out = (float*)d_out;

    float* ws = (float*)d_ws;
    float* pt      = ws;                                  // 32 KB
    uint4* qpack   = (uint4*)(ws + 8192);                 // 2048*2*64*16B = 4 MB
    uint4* w2pack  = (uint4*)(ws + 8192 + 1048576 + 16384); // after qpack

    prep_kernel<<<521, 256, 0, stream>>>(rv, W1, b1, W2, pt, qpack, w2pack);

    dim3 grid(NN / 128, NN / ITILE, NB);
    rpe_kernel<<<grid, 256, 0, stream>>>(pt, qpack, w2pack, gamma, beta, b2, out);
}

// Round 7
// 40.013 us; speedup vs baseline: 5.0806x; 1.0013x over previous
//
#include <hip/hip_runtime.h>
#include <math.h>

#define NB 2
#define NN 1024
#define NH 64
#define NK 8
#define ITILE 8

typedef float f32x2 __attribute__((ext_vector_type(2)));
typedef float f32x16 __attribute__((ext_vector_type(16)));
typedef _Float16 half8 __attribute__((ext_vector_type(8)));
typedef _Float16 half2t __attribute__((ext_vector_type(2)));
typedef __fp16 fp16x2 __attribute__((ext_vector_type(2)));
typedef unsigned u32x2 __attribute__((ext_vector_type(2)));

union FragU { uint32_t u[4]; uint4 q; half8 h; };
union H2U  { half2t h; fp16x2 p; uint32_t u; };
union C32U { f32x16 v; f32x2 d[8]; float f[16]; };

static __device__ __forceinline__ uint32_t pk_rne(float a, float b) {
    half2t t; t[0] = (_Float16)a; t[1] = (_Float16)b;
    H2U r; r.h = t; return r.u;
}

// lane-half exchange: returns w0 = [a_lo | b_from_lo], w2 = [a_from_hi | b_hi]
static __device__ __forceinline__ void half_swap(uint32_t a, uint32_t b,
                                                 uint32_t& w0, uint32_t& w2) {
#if __has_builtin(__builtin_amdgcn_permlane32_swap)
    u32x2 s = __builtin_amdgcn_permlane32_swap(a, b, false, false);
    w0 = s[0]; w2 = s[1];
#else
    const int hi = (threadIdx.x & 63) >> 5;
    uint32_t pa = __shfl_xor(a, 32), pb = __shfl_xor(b, 32);
    w0 = hi ? pb : a;
    w2 = hi ? b : pa;
#endif
}

// ---------------- prep ----------------
// blocks 0..7   : pt[b][n] = (x, y, cos h, sin h) f32
// blocks 8..519 : qpack A1-frags (32x32x16), 64 lane-slots per (b,i,tile):
//                 slot h&31 = 16B {(qc,qs),(qx,qy),(w0,cn),0}; slots 32..63 = 0
// block 520     : w2pack A2-frags (32x32x16), 4 K-chunks:
//                 chunk c, lane l: row k_out=l&31 (<8 real), k e=0..7 -> h=16c+8*(l>>5)+e
__global__ void prep_kernel(const float* __restrict__ rv,
                            const float* __restrict__ W1,
                            const float* __restrict__ b1,
                            const float* __restrict__ W2,
                            float* __restrict__ pt,
                            uint4* __restrict__ qpack,
                            uint4* __restrict__ w2pack) {
    const int tid = threadIdx.x;
    const int bid = blockIdx.x;
    if (bid < 8) {
        const int idx = bid * 256 + tid;  // 0..2047
        const float x0 = rv[idx*4+0], y0 = rv[idx*4+1];
        const float vx = rv[idx*4+2] - x0, vy = rv[idx*4+3] - y0;
        const float rinv = rsqrtf(fmaf(vx, vx, vy * vy));
        float4 o; o.x = x0; o.y = y0; o.z = vx * rinv; o.w = vy * rinv;
        reinterpret_cast<float4*>(pt)[idx] = o;
    } else if (bid < 520) {
        __shared__ float mean[6];
        if (tid < 5)       { float m = 0.f; for (int h = 0; h < NH; ++h) m += W1[tid*NH+h]; mean[tid] = m * (1.f/NH); }
        else if (tid == 5) { float m = 0.f; for (int h = 0; h < NH; ++h) m += b1[h];        mean[5]   = m * (1.f/NH); }
        __syncthreads();
        const int gid = (bid - 8) * 256 + tid;     // (b,i,h)
        const int b = gid >> 16, i = (gid >> 6) & 1023, h = gid & 63;
        const float x0 = rv[(b*NN+i)*4+0], y0 = rv[(b*NN+i)*4+1];
        const float vx = rv[(b*NN+i)*4+2] - x0, vy = rv[(b*NN+i)*4+3] - y0;
        const float rinv = rsqrtf(fmaf(vx, vx, vy * vy));
        const float ci = vx * rinv, si = vy * rinv;
        const float w0 = W1[0*NH+h]-mean[0], w1 = W1[1*NH+h]-mean[1], w2 = W1[2*NH+h]-mean[2],
                    w3 = W1[3*NH+h]-mean[3], w4 = W1[4*NH+h]-mean[4];
        const float bb = b1[h] - mean[5];
        const float qc = fmaf(w1, ci,  w2 * si);
        const float qs = fmaf(w1, si, -w2 * ci);
        const float qx = fmaf(-w3, ci,  w4 * si);
        const float qy = fmaf(-w3, si, -w4 * ci);
        const float cn = fmaf(w3, fmaf(x0, ci, y0 * si), fmaf(w4, fmaf(y0, ci, -x0 * si), bb));
        uint4 v;
        v.x = pk_rne(qc, qs); v.y = pk_rne(qx, qy); v.z = pk_rne(w0, cn); v.w = 0u;
        const size_t qb = ((size_t)(b*NN + i)*2 + (h >> 5))*64 + (h & 31);
        qpack[qb] = v;
        qpack[qb + 32] = make_uint4(0,0,0,0);
    } else {
        // w2pack: 4 chunks x 64 lanes
        const int c = tid >> 6, l = tid & 63;
        const int row = l & 31;
        const int hb = 16*c + 8*(l >> 5);
        uint32_t dw[4];
        for (int t = 0; t < 4; ++t) {
            const int h0 = hb + 2*t;
            const float a = (row < 8) ? W2[h0*NK + row]     : 0.f;
            const float d = (row < 8) ? W2[(h0+1)*NK + row] : 0.f;
            dw[t] = pk_rne(a, d);
        }
        uint4 v; v.x = dw[0]; v.y = dw[1]; v.z = dw[2]; v.w = dw[3];
        w2pack[c*64 + l] = v;
    }
}

// ---------------- main ----------------
// Per wave: 32 j, ITILE i. GEMM1: 2x mfma_32x32x16 (A=Q, B=features).
// LN: mu==0 exact (pre-centered W1); inv = rsqrt(E[x^2]+eps), 1 shfl.
// Normalize+relu in packed f16. Y C-layout -> B-layout via 8 permlane32_swap
// (no LDS at all). GEMM2: 4x mfma_32x32x16 vs W2 chunk frags. 4 full-wave
// coalesced dword stores per iter.
__global__ __launch_bounds__(256, 3) void rpe_kernel(
    const float* __restrict__ pt,
    const uint4* __restrict__ qpack,
    const uint4* __restrict__ w2pack,
    const float* __restrict__ gamma,
    const float* __restrict__ beta,
    const float* __restrict__ b2,
    float* __restrict__ out) {
    const int tid  = threadIdx.x;
    const int wave = tid >> 6;
    const int lane = tid & 63;
    const int jj   = lane & 31;
    const int hi   = lane >> 5;
    const int b  = blockIdx.z;
    const int j0 = blockIdx.x * 128 + wave * 32;
    const int iBase = blockIdx.y * ITILE;

    const uint32_t hm = hi ? 0u : 0xFFFFFFFFu;

    const float4 pj = reinterpret_cast<const float4*>(pt)[b*NN + j0 + jj];
    const float xj = pj.x, yj = pj.y;
    const uint32_t d0 = pk_rne(pj.z, pj.w) & hm;
    const uint32_t d1 = pk_rne(xj, yj) & hm;

    // gamma/beta fp16 pairs: word (T,m) -> rows h0,h0+1 ; h0 = 32T+8(m>>1)+2(m&1)+4hi
    uint32_t gph[16], bph[16];
#pragma unroll
    for (int T = 0; T < 2; ++T)
#pragma unroll
        for (int m = 0; m < 8; ++m) {
            const int h0 = 32*T + 8*(m>>1) + 2*(m&1) + 4*hi;
            gph[T*8+m] = pk_rne(gamma[h0], gamma[h0+1]);
            bph[T*8+m] = pk_rne(beta[h0],  beta[h0+1]);
        }

    FragU a2[4];
#pragma unroll
    for (int c = 0; c < 4; ++c) a2[c].q = w2pack[c*64 + lane];
    float b2v[4];
#pragma unroll
    for (int r = 0; r < 4; ++r) b2v[r] = b2[4*hi + r];

    const uint4* qrow = qpack + (size_t)(b*NN + iBase) * 128;
    const float4* ptb = reinterpret_cast<const float4*>(pt) + b*NN + iBase;

    uint4 qA = qrow[lane];
    uint4 qB = qrow[64 + lane];
    float4 piv = ptb[0];

    const f32x16 z16 = {0,0,0,0,0,0,0,0,0,0,0,0,0,0,0,0};
    half2t z2; z2[0] = (_Float16)0.f; z2[1] = (_Float16)0.f;
    const size_t plane = (size_t)NN * NN;
    float* op = out + (size_t)(b*NK + 4*hi)*plane + (size_t)iBase*NN + (j0 + jj);

    for (int ii = 0; ii < ITILE; ++ii) {
        FragU qf0, qf1;
        qf0.q = qA; qf1.q = qB;
        const float pix = piv.x, piy = piv.y;
        const int nx = (ii < ITILE-1) ? (ii + 1) : (ITILE-1);
        qA = qrow[nx*128 + lane];
        qB = qrow[nx*128 + 64 + lane];
        piv = ptb[nx];

        const float dx = pix - xj, dy = piy - yj;
        const float g0v = logf(sqrtf(fmaf(dx, dx, dy * dy)) + 1e-5f);
        H2U d2u; d2u.p = __builtin_amdgcn_cvt_pkrtz(g0v, 1.0f);
        FragU bf; bf.u[0] = d0; bf.u[1] = d1; bf.u[2] = d2u.u & hm; bf.u[3] = 0u;

        C32U cA, cB;
        cA.v = __builtin_amdgcn_mfma_f32_32x32x16_f16(qf0.h, bf.h, z16, 0, 0, 0);
        cB.v = __builtin_amdgcn_mfma_f32_32x32x16_f16(qf1.h, bf.h, z16, 0, 0, 0);

        // sumsq (mu == 0 exactly by pre-centering) + early cvt to f16
        uint32_t xw[16];
        f32x2 q0 = cA.d[0]*cA.d[0], q1 = cA.d[1]*cA.d[1], q2 = cA.d[2]*cA.d[2], q3 = cA.d[3]*cA.d[3];
        q0 = __builtin_elementwise_fma(cA.d[4], cA.d[4], q0);
        q1 = __builtin_elementwise_fma(cA.d[5], cA.d[5], q1);
        q2 = __builtin_elementwise_fma(cA.d[6], cA.d[6], q2);
        q3 = __builtin_elementwise_fma(cA.d[7], cA.d[7], q3);
#pragma unroll
        for (int m = 0; m < 8; ++m) {
            H2U t; t.p = __builtin_amdgcn_cvt_pkrtz(cA.d[m][0], cA.d[m][1]);
            xw[m] = t.u;
        }
        q0 = __builtin_elementwise_fma(cB.d[0], cB.d[0], q0);
        q1 = __builtin_elementwise_fma(cB.d[1], cB.d[1], q1);
        q2 = __builtin_elementwise_fma(cB.d[2], cB.d[2], q2);
        q3 = __builtin_elementwise_fma(cB.d[3], cB.d[3], q3);
        q0 = __builtin_elementwise_fma(cB.d[4], cB.d[4], q0);
        q1 = __builtin_elementwise_fma(cB.d[5], cB.d[5], q1);
        q2 = __builtin_elementwise_fma(cB.d[6], cB.d[6], q2);
        q3 = __builtin_elementwise_fma(cB.d[7], cB.d[7], q3);
#pragma unroll
        for (int m = 0; m < 8; ++m) {
            H2U t; t.p = __builtin_amdgcn_cvt_pkrtz(cB.d[m][0], cB.d[m][1]);
            xw[8+m] = t.u;
        }
        q0 += q1; q2 += q3; q0 += q2;
        float sq = q0[0] + q0[1];
        sq += __shfl_xor(sq, 32);
        const float inv = rsqrtf(fmaf(sq, 1.f/64.f, 1e-5f));
        H2U inv2u; inv2u.p = __builtin_amdgcn_cvt_pkrtz(inv, inv);
        const half2t inv2 = inv2u.h;

        // normalize + affine + relu (packed f16)
        uint32_t yw[16];
#pragma unroll
        for (int m = 0; m < 16; ++m) {
            H2U x; x.u = xw[m];
            half2t xh = x.h * inv2;
            H2U gg, bb; gg.u = gph[m]; bb.u = bph[m];
            half2t y = __builtin_elementwise_fma(xh, gg.h, bb.h);
            y = __builtin_elementwise_max(y, z2);
            H2U o; o.h = y; yw[m] = o.u;
        }

        // GEMM2: assemble B-frags via lane-half swaps, 4 chained MFMAs
        C32U c2;
        {
            f32x16 acc = z16;
#pragma unroll
            for (int c = 0; c < 4; ++c) {
                uint32_t w0, w1, w2, w3;
                half_swap(yw[4*c + 0], yw[4*c + 2], w0, w2);
                half_swap(yw[4*c + 1], yw[4*c + 3], w1, w3);
                FragU Bf; Bf.u[0] = w0; Bf.u[1] = w1; Bf.u[2] = w2; Bf.u[3] = w3;
                acc = __builtin_amdgcn_mfma_f32_32x32x16_f16(a2[c].h, Bf.h, acc, 0, 0, 0);
            }
            c2.v = acc;
        }

        // store: rows k_out = 4hi+0..3, col j (full wave, coalesced 256B runs)
        op[0]         = c2.f[0] + b2v[0];
        op[plane]     = c2.f[1] + b2v[1];
        op[2*plane]   = c2.f[2] + b2v[2];
        op[3*plane]   = c2.f[3] + b2v[3];
        op += NN;
    }
}

extern "C" void kernel_launch(void* const* d_in, const int* in_sizes, int n_in,
                              void* d_out, int out_size, void* d_ws, size_t ws_size,
                              hipStream_t stream) {
    const float* rv    = (const float*)d_in[0];
    const float* W1    = (const float*)d_in[1];
    const float* b1    = (const float*)d_in[2];
    const float* gamma = (const float*)d_in[3];
    const float* beta  = (const float*)d_in[4];
    const float* W2    = (const float*)d_in[5];
    const float* b2    = (const float*)d_in[6];
    float* out = (float*)d_out;

    float* ws = (float*)d_ws;
    float* pt      = ws;                                    // 32 KB
    uint4* qpack   = (uint4*)(ws + 8192);                   // 2048*2*64*16B = 4 MB
    uint4* w2pack  = (uint4*)(ws + 8192 + 1048576 + 16384); // 4 KB

    prep_kernel<<<521, 256, 0, stream>>>(rv, W1, b1, W2, pt, qpack, w2pack);

    dim3 grid(NN / 128, NN / ITILE, NB);
    rpe_kernel<<<grid, 256, 0, stream>>>(pt, qpack, w2pack, gamma, beta, b2, out);
}